// Round 15
// baseline (229.952 us; speedup 1.0000x reference)
//
#include <hip/hip_runtime.h>

typedef __bf16 bf16_t;
typedef bf16_t bf16x8 __attribute__((ext_vector_type(8)));
typedef bf16_t bf16x4 __attribute__((ext_vector_type(4)));
typedef float f32x4 __attribute__((ext_vector_type(4)));

// load 8 contiguous elements as bf16x8 (fp32 source converts in-register)
__device__ inline bf16x8 ld8(const float* p) {
    f32x4 a = *reinterpret_cast<const f32x4*>(p);
    f32x4 b = *reinterpret_cast<const f32x4*>(p + 4);
    bf16x8 r = { (bf16_t)a[0], (bf16_t)a[1], (bf16_t)a[2], (bf16_t)a[3],
                 (bf16_t)b[0], (bf16_t)b[1], (bf16_t)b[2], (bf16_t)b[3] };
    return r;
}
__device__ inline bf16x8 ld8(const bf16_t* p) {
    return *reinterpret_cast<const bf16x8*>(p);
}

// ---------------- GEMM: C = A * B^T; 64x64 tile, BK=64, pipelined, XCD remap ----------------
// SIDE=true adds one-pass side jobs: w_proj fp32->bf16 convert and out := bias (proj fused later).
template <typename AT, typename BT, typename OUT_T, bool SIDE>
__global__ __launch_bounds__(256) void gemm_bt(
    const AT* __restrict__ A, const BT* __restrict__ B,
    OUT_T* __restrict__ C,
    int K, int lda, int ldb, int ldc,
    const float* __restrict__ wp_src, bf16_t* __restrict__ wp_dst,
    float* __restrict__ out_init, const float* __restrict__ bias_init)
{
    if (SIDE) {
        const int g = blockIdx.x * 256 + threadIdx.x;          // 73728 threads
        *reinterpret_cast<bf16x8*>(wp_dst + g * 8) = ld8(wp_src + g * 8);  // 589824 = 73728*8
        for (int e = g; e < 393216; e += 73728)
            out_init[e] = bias_init[e % 768];
    }

    const int l  = blockIdx.x;
    const int lp = (l & 7) * (gridDim.x >> 3) + (l >> 3);   // bijective XCD chunking (total%8==0)
    const int m0 = (lp & 7) * 64;                           // 8 m-tiles (M=512)
    const int n0 = (lp >> 3) * 64;

    __shared__ __align__(16) bf16_t As[64][72];   // +8 pad -> 2-way bank alias (free)
    __shared__ __align__(16) bf16_t Bs[64][72];

    const int tid  = threadIdx.x;
    const int lane = tid & 63;
    const int wave = tid >> 6;
    const int srow = tid >> 3;          // 0..31 (second chunk: +32)
    const int soff = (tid & 7) * 8;     // 0,8,..,56

    bf16x8 rA0, rA1, rB0, rB1;
    rA0 = ld8(&A[(long)(m0 + srow)      * lda + soff]);
    rA1 = ld8(&A[(long)(m0 + srow + 32) * lda + soff]);
    rB0 = ld8(&B[(long)(n0 + srow)      * ldb + soff]);
    rB1 = ld8(&B[(long)(n0 + srow + 32) * ldb + soff]);

    f32x4 acc[4] = {};

    for (int k0 = 0; k0 < K; k0 += 64) {
        *reinterpret_cast<bf16x8*>(&As[srow][soff])      = rA0;
        *reinterpret_cast<bf16x8*>(&As[srow + 32][soff]) = rA1;
        *reinterpret_cast<bf16x8*>(&Bs[srow][soff])      = rB0;
        *reinterpret_cast<bf16x8*>(&Bs[srow + 32][soff]) = rB1;
        __syncthreads();

        if (k0 + 64 < K) {              // issue next-tile loads; consumed after next barrier
            rA0 = ld8(&A[(long)(m0 + srow)      * lda + k0 + 64 + soff]);
            rA1 = ld8(&A[(long)(m0 + srow + 32) * lda + k0 + 64 + soff]);
            rB0 = ld8(&B[(long)(n0 + srow)      * ldb + k0 + 64 + soff]);
            rB1 = ld8(&B[(long)(n0 + srow + 32) * ldb + k0 + 64 + soff]);
        }

#pragma unroll
        for (int ks = 0; ks < 64; ks += 32) {
            bf16x8 af = *reinterpret_cast<const bf16x8*>(&As[wave * 16 + (lane & 15)][(lane >> 4) * 8 + ks]);
#pragma unroll
            for (int nf = 0; nf < 4; ++nf) {
                bf16x8 bfr = *reinterpret_cast<const bf16x8*>(&Bs[nf * 16 + (lane & 15)][(lane >> 4) * 8 + ks]);
                acc[nf] = __builtin_amdgcn_mfma_f32_16x16x32_bf16(af, bfr, acc[nf], 0, 0, 0);
            }
        }
        __syncthreads();
    }

    const int crow0 = m0 + wave * 16 + (lane >> 4) * 4;
    const int ccol0 = n0 + (lane & 15);
#pragma unroll
    for (int nf = 0; nf < 4; ++nf) {
        const int col = ccol0 + nf * 16;
#pragma unroll
        for (int v = 0; v < 4; ++v) {
            C[(long)(crow0 + v) * ldc + col] = (OUT_T)(acc[nf][v]);
        }
    }
}

// ---------------- fused S = softmax((q/8) k^T) -> bf16: grid (24 bh, 4 m-tiles) ----------------
__global__ __launch_bounds__(256) void qk_softmax(
    const bf16_t* __restrict__ qkv,   // [B,256,2304]
    bf16_t* __restrict__ probs)       // [24,256,256] bf16
{
    const int bh = blockIdx.x;
    const int b = bh / 12, h = bh % 12;
    const int m0 = blockIdx.y * 64;
    const bf16_t* qbase = qkv + (long)b * 589824 + h * 64;
    const bf16_t* kbase = qkv + (long)b * 589824 + 768 + h * 64;

    __shared__ __align__(16) bf16_t Qs[64][72];
    __shared__ __align__(16) bf16_t Ks[256][72];

    const int t = threadIdx.x;
#pragma unroll
    for (int c = 0; c < 2; ++c) {
        const int chunk = c * 256 + t;
        const int row = chunk >> 3, off = (chunk & 7) * 8;
        *reinterpret_cast<uint4*>(&Qs[row][off]) =
            *reinterpret_cast<const uint4*>(qbase + (long)(m0 + row) * 2304 + off);
    }
#pragma unroll
    for (int c = 0; c < 8; ++c) {
        const int chunk = c * 256 + t;
        const int row = chunk >> 3, off = (chunk & 7) * 8;
        *reinterpret_cast<uint4*>(&Ks[row][off]) =
            *reinterpret_cast<const uint4*>(kbase + (long)row * 2304 + off);
    }
    __syncthreads();

    const int lane = t & 63, wave = t >> 6;
    f32x4 acc[16] = {};
#pragma unroll
    for (int ks = 0; ks < 64; ks += 32) {
        bf16x8 af = *reinterpret_cast<const bf16x8*>(&Qs[wave * 16 + (lane & 15)][(lane >> 4) * 8 + ks]);
#pragma unroll
        for (int nf = 0; nf < 16; ++nf) {
            bf16x8 bfr = *reinterpret_cast<const bf16x8*>(&Ks[nf * 16 + (lane & 15)][(lane >> 4) * 8 + ks]);
            acc[nf] = __builtin_amdgcn_mfma_f32_16x16x32_bf16(af, bfr, acc[nf], 0, 0, 0);
        }
    }

    float inv[4];
#pragma unroll
    for (int v = 0; v < 4; ++v) {
        float mm = -1e30f;
#pragma unroll
        for (int nf = 0; nf < 16; ++nf) { acc[nf][v] *= 0.125f; mm = fmaxf(mm, acc[nf][v]); }
#pragma unroll
        for (int o = 1; o < 16; o <<= 1) mm = fmaxf(mm, __shfl_xor(mm, o));
        float s = 0.0f;
#pragma unroll
        for (int nf = 0; nf < 16; ++nf) { float e = __expf(acc[nf][v] - mm); acc[nf][v] = e; s += e; }
#pragma unroll
        for (int o = 1; o < 16; o <<= 1) s += __shfl_xor(s, o);
        inv[v] = 1.0f / s;
    }

    bf16_t* prow = probs + ((long)bh * 256 + m0 + wave * 16 + (lane >> 4) * 4) * 256 + (lane & 15);
#pragma unroll
    for (int nf = 0; nf < 16; ++nf) {
#pragma unroll
        for (int v = 0; v < 4; ++v) {
            prow[(long)v * 256 + nf * 16] = (bf16_t)(acc[nf][v] * inv[v]);
        }
    }
}

// ---------------- fused: attnd + proj partial. out[i,n] += (attn@(v+d))[i,cslice] . w_proj[n,cslice] ----------------
// NT d loads (r14 proved NT protects L2 working set: +16.5us without it).
// out pre-initialized to b_proj by gemm1's side job; 3 cc-blocks atomicAdd their partials.
__global__ __launch_bounds__(256) void attnd_kernel(
    const bf16_t* __restrict__ attn,  // [24,256,256] bf16 probs
    const bf16_t* __restrict__ qkv,   // [B,256,2304]
    const float* __restrict__ d,      // [B,256,256,768]
    const bf16_t* __restrict__ wpb,   // [768,768] bf16 w_proj
    float* __restrict__ out)          // [B,256,768] fp32, preset to bias
{
    const int bi = blockIdx.x;
    const int b  = bi >> 8;
    const int i  = bi & 255;
    const int cc = blockIdx.y;
    const int t  = threadIdx.x;
    const int lane = t & 63, wave = t >> 6;

    __shared__ float attn_s[4 * 257];
    __shared__ float pw[4][256];
    __shared__ float oh_lds[256];

#pragma unroll
    for (int q = 0; q < 4; ++q) {
        attn_s[q * 257 + t] = (float)attn[(((long)(b * 12 + cc * 4 + q)) * 256 + i) * 256 + t];
    }
    __syncthreads();

    const int c0 = cc * 256 + lane * 4;
    const float* arow = attn_s + (lane >> 4) * 257;
    const int jb = wave * 64;
    const f32x4* dp = reinterpret_cast<const f32x4*>(d + (long)bi * 196608 + (long)jb * 768 + c0);
    const bf16_t* vp = qkv + (long)b * 589824 + (long)jb * 2304 + 1536 + c0;

    f32x4 acc = {};
#pragma unroll 8
    for (int jj = 0; jj < 64; ++jj) {
        f32x4 dv = __builtin_nontemporal_load(dp + (long)jj * 192);
        bf16x4 vv = *reinterpret_cast<const bf16x4*>(vp + (long)jj * 2304);
        float a = arow[jb + jj];
        acc[0] = fmaf(a, dv[0] + (float)vv[0], acc[0]);
        acc[1] = fmaf(a, dv[1] + (float)vv[1], acc[1]);
        acc[2] = fmaf(a, dv[2] + (float)vv[2], acc[2]);
        acc[3] = fmaf(a, dv[3] + (float)vv[3], acc[3]);
    }

#pragma unroll
    for (int e = 0; e < 4; ++e) pw[wave][lane * 4 + e] = acc[e];
    __syncthreads();

    // reduce partials -> oh chunk (c_local = t)
    oh_lds[t] = pw[0][t] + pw[1][t] + pw[2][t] + pw[3][t];
    __syncthreads();

    // proj partial: thread t handles n = t, t+256, t+512
#pragma unroll
    for (int r = 0; r < 3; ++r) {
        const int n = r * 256 + t;
        const bf16_t* wp = wpb + (long)n * 768 + cc * 256;
        float s = 0.0f;
#pragma unroll
        for (int c8 = 0; c8 < 32; ++c8) {
            bf16x8 w = *reinterpret_cast<const bf16x8*>(wp + c8 * 8);
#pragma unroll
            for (int u = 0; u < 8; ++u)
                s = fmaf(oh_lds[c8 * 8 + u], (float)w[u], s);
        }
        atomicAdd(out + (long)bi * 768 + n, s);
    }
}

// ---------------- launch ----------------
extern "C" void kernel_launch(void* const* d_in, const int* in_sizes, int n_in,
                              void* d_out, int out_size, void* d_ws, size_t ws_size,
                              hipStream_t stream) {
    const float* x      = (const float*)d_in[0];   // [2,256,768]
    const float* d      = (const float*)d_in[1];   // [2,256,256,768]
    const float* w_qkv  = (const float*)d_in[2];   // [2304,768]
    const float* w_proj = (const float*)d_in[3];   // [768,768]
    const float* b_proj = (const float*)d_in[4];   // [768]
    float* out = (float*)d_out;                    // [2,256,768]

    char* ws = (char*)d_ws;
    bf16_t* qkvb  = (bf16_t*)(ws);                 //  512x2304 bf16
    bf16_t* probs = (bf16_t*)(ws + 2359296);       //  24x256x256 bf16
    bf16_t* wpb   = (bf16_t*)(ws + 5505024);       //  768x768 bf16

    // 1. qkv = x @ w_qkv^T -> bf16; side jobs: w_proj->bf16, out := bias
    gemm_bt<float, float, bf16_t, true><<<288, 256, 0, stream>>>(
        x, w_qkv, qkvb, 768, 768, 768, 2304, w_proj, wpb, out, b_proj);

    // 2. probs = softmax((q/8) k^T) -> bf16 [24,256,256]
    qk_softmax<<<dim3(24, 4), 256, 0, stream>>>(qkvb, probs);

    // 3. out += (attn @ (v + d_pair)) @ w_proj^T   (proj fused, atomicAdd over cc)
    attnd_kernel<<<dim3(512, 3), 256, 0, stream>>>(probs, qkvb, d, wpb, out);
}

// Round 16
// 98.273 us; speedup vs baseline: 2.3399x; 2.3399x over previous
//
#include <hip/hip_runtime.h>

typedef __bf16 bf16_t;
typedef bf16_t bf16x8 __attribute__((ext_vector_type(8)));
typedef bf16_t bf16x4 __attribute__((ext_vector_type(4)));
typedef float f32x4 __attribute__((ext_vector_type(4)));

// load 8 contiguous elements as bf16x8 (fp32 source converts in-register)
__device__ inline bf16x8 ld8(const float* p) {
    f32x4 a = *reinterpret_cast<const f32x4*>(p);
    f32x4 b = *reinterpret_cast<const f32x4*>(p + 4);
    bf16x8 r = { (bf16_t)a[0], (bf16_t)a[1], (bf16_t)a[2], (bf16_t)a[3],
                 (bf16_t)b[0], (bf16_t)b[1], (bf16_t)b[2], (bf16_t)b[3] };
    return r;
}
__device__ inline bf16x8 ld8(const bf16_t* p) {
    return *reinterpret_cast<const bf16x8*>(p);
}

// ---------------- GEMM: C = A * B^T (+bias); 64x64 tile, BK=64, 2-deep prefetch ----------------
// K % 128 == 0. Loads for tile k are issued 2 iterations ahead (~2x iteration body),
// fully covering the ~700cy dependent-load latency that 1-deep prefetch exposed.
template <typename AT, typename BT, typename OUT_T, bool HAS_BIAS>
__global__ __launch_bounds__(256) void gemm_bt(
    const AT* __restrict__ A, const BT* __restrict__ B,
    OUT_T* __restrict__ C, const float* __restrict__ bias,
    int K, int lda, int ldb, int ldc)
{
    const int l  = blockIdx.x;
    const int lp = (l & 7) * (gridDim.x >> 3) + (l >> 3);   // bijective XCD chunking (total%8==0)
    const int m0 = (lp & 7) * 64;                           // 8 m-tiles (M=512)
    const int n0 = (lp >> 3) * 64;

    __shared__ __align__(16) bf16_t As[64][72];   // +8 pad -> 2-way bank alias (free)
    __shared__ __align__(16) bf16_t Bs[64][72];

    const int tid  = threadIdx.x;
    const int lane = tid & 63;
    const int wave = tid >> 6;
    const int srow = tid >> 3;          // 0..31 (second chunk: +32)
    const int soff = (tid & 7) * 8;     // 0,8,..,56

    const AT* a0 = &A[(long)(m0 + srow) * lda + soff];
    const AT* a1 = &A[(long)(m0 + srow + 32) * lda + soff];
    const BT* b0 = &B[(long)(n0 + srow) * ldb + soff];
    const BT* b1 = &B[(long)(n0 + srow + 32) * ldb + soff];

    bf16x8 rAa0 = ld8(a0),      rAa1 = ld8(a1),      rAb0 = ld8(b0),      rAb1 = ld8(b1);
    bf16x8 rBa0 = ld8(a0 + 64), rBa1 = ld8(a1 + 64), rBb0 = ld8(b0 + 64), rBb1 = ld8(b1 + 64);

    f32x4 acc[4] = {};

    for (int k0 = 0; k0 < K; k0 += 128) {
        // ---- even tile (k0), staged from reg-set A ----
        *reinterpret_cast<bf16x8*>(&As[srow][soff])      = rAa0;
        *reinterpret_cast<bf16x8*>(&As[srow + 32][soff]) = rAa1;
        *reinterpret_cast<bf16x8*>(&Bs[srow][soff])      = rAb0;
        *reinterpret_cast<bf16x8*>(&Bs[srow + 32][soff]) = rAb1;
        __syncthreads();
        if (k0 + 128 < K) {             // load k0+128 into reg-set A (consumed 2 iters later)
            rAa0 = ld8(a0 + k0 + 128); rAa1 = ld8(a1 + k0 + 128);
            rAb0 = ld8(b0 + k0 + 128); rAb1 = ld8(b1 + k0 + 128);
        }
#pragma unroll
        for (int ks = 0; ks < 64; ks += 32) {
            bf16x8 af = *reinterpret_cast<const bf16x8*>(&As[wave * 16 + (lane & 15)][(lane >> 4) * 8 + ks]);
#pragma unroll
            for (int nf = 0; nf < 4; ++nf) {
                bf16x8 bfr = *reinterpret_cast<const bf16x8*>(&Bs[nf * 16 + (lane & 15)][(lane >> 4) * 8 + ks]);
                acc[nf] = __builtin_amdgcn_mfma_f32_16x16x32_bf16(af, bfr, acc[nf], 0, 0, 0);
            }
        }
        __syncthreads();

        // ---- odd tile (k0+64), staged from reg-set B ----
        *reinterpret_cast<bf16x8*>(&As[srow][soff])      = rBa0;
        *reinterpret_cast<bf16x8*>(&As[srow + 32][soff]) = rBa1;
        *reinterpret_cast<bf16x8*>(&Bs[srow][soff])      = rBb0;
        *reinterpret_cast<bf16x8*>(&Bs[srow + 32][soff]) = rBb1;
        __syncthreads();
        if (k0 + 192 < K) {             // load k0+192 into reg-set B
            rBa0 = ld8(a0 + k0 + 192); rBa1 = ld8(a1 + k0 + 192);
            rBb0 = ld8(b0 + k0 + 192); rBb1 = ld8(b1 + k0 + 192);
        }
#pragma unroll
        for (int ks = 0; ks < 64; ks += 32) {
            bf16x8 af = *reinterpret_cast<const bf16x8*>(&As[wave * 16 + (lane & 15)][(lane >> 4) * 8 + ks]);
#pragma unroll
            for (int nf = 0; nf < 4; ++nf) {
                bf16x8 bfr = *reinterpret_cast<const bf16x8*>(&Bs[nf * 16 + (lane & 15)][(lane >> 4) * 8 + ks]);
                acc[nf] = __builtin_amdgcn_mfma_f32_16x16x32_bf16(af, bfr, acc[nf], 0, 0, 0);
            }
        }
        __syncthreads();
    }

    const int crow0 = m0 + wave * 16 + (lane >> 4) * 4;
    const int ccol0 = n0 + (lane & 15);
#pragma unroll
    for (int nf = 0; nf < 4; ++nf) {
        const int col = ccol0 + nf * 16;
        const float bv = HAS_BIAS ? bias[col] : 0.0f;
#pragma unroll
        for (int v = 0; v < 4; ++v) {
            C[(long)(crow0 + v) * ldc + col] = (OUT_T)(acc[nf][v] + bv);
        }
    }
}

// ---------------- fused S = softmax((q/8) k^T) -> bf16: grid (24 bh, 4 m-tiles) ----------------
__global__ __launch_bounds__(256) void qk_softmax(
    const bf16_t* __restrict__ qkv,   // [B,256,2304]
    bf16_t* __restrict__ probs)       // [24,256,256] bf16
{
    const int bh = blockIdx.x;
    const int b = bh / 12, h = bh % 12;
    const int m0 = blockIdx.y * 64;
    const bf16_t* qbase = qkv + (long)b * 589824 + h * 64;
    const bf16_t* kbase = qkv + (long)b * 589824 + 768 + h * 64;

    __shared__ __align__(16) bf16_t Qs[64][72];
    __shared__ __align__(16) bf16_t Ks[256][72];

    const int t = threadIdx.x;
#pragma unroll
    for (int c = 0; c < 2; ++c) {
        const int chunk = c * 256 + t;
        const int row = chunk >> 3, off = (chunk & 7) * 8;
        *reinterpret_cast<uint4*>(&Qs[row][off]) =
            *reinterpret_cast<const uint4*>(qbase + (long)(m0 + row) * 2304 + off);
    }
#pragma unroll
    for (int c = 0; c < 8; ++c) {
        const int chunk = c * 256 + t;
        const int row = chunk >> 3, off = (chunk & 7) * 8;
        *reinterpret_cast<uint4*>(&Ks[row][off]) =
            *reinterpret_cast<const uint4*>(kbase + (long)row * 2304 + off);
    }
    __syncthreads();

    const int lane = t & 63, wave = t >> 6;
    f32x4 acc[16] = {};
#pragma unroll
    for (int ks = 0; ks < 64; ks += 32) {
        bf16x8 af = *reinterpret_cast<const bf16x8*>(&Qs[wave * 16 + (lane & 15)][(lane >> 4) * 8 + ks]);
#pragma unroll
        for (int nf = 0; nf < 16; ++nf) {
            bf16x8 bfr = *reinterpret_cast<const bf16x8*>(&Ks[nf * 16 + (lane & 15)][(lane >> 4) * 8 + ks]);
            acc[nf] = __builtin_amdgcn_mfma_f32_16x16x32_bf16(af, bfr, acc[nf], 0, 0, 0);
        }
    }

    float inv[4];
#pragma unroll
    for (int v = 0; v < 4; ++v) {
        float mm = -1e30f;
#pragma unroll
        for (int nf = 0; nf < 16; ++nf) { acc[nf][v] *= 0.125f; mm = fmaxf(mm, acc[nf][v]); }
#pragma unroll
        for (int o = 1; o < 16; o <<= 1) mm = fmaxf(mm, __shfl_xor(mm, o));
        float s = 0.0f;
#pragma unroll
        for (int nf = 0; nf < 16; ++nf) { float e = __expf(acc[nf][v] - mm); acc[nf][v] = e; s += e; }
#pragma unroll
        for (int o = 1; o < 16; o <<= 1) s += __shfl_xor(s, o);
        inv[v] = 1.0f / s;
    }

    bf16_t* prow = probs + ((long)bh * 256 + m0 + wave * 16 + (lane >> 4) * 4) * 256 + (lane & 15);
#pragma unroll
    for (int nf = 0; nf < 16; ++nf) {
#pragma unroll
        for (int v = 0; v < 4; ++v) {
            prow[(long)v * 256 + nf * 16] = (bf16_t)(acc[nf][v] * inv[v]);
        }
    }
}

// ---------------- fused: oh[b,i,c] = sum_j attn * (v + d)  (roofline: ~62.5us, NT required) ----------------
__global__ __launch_bounds__(256) void attnd_kernel(
    const bf16_t* __restrict__ attn,  // [24,256,256] bf16 probs
    const bf16_t* __restrict__ qkv,   // [B,256,2304]
    const float* __restrict__ d,      // [B,256,256,768]
    bf16_t* __restrict__ oh)          // [B,256,768]
{
    const int bi = blockIdx.x;
    const int b  = bi >> 8;
    const int i  = bi & 255;
    const int cc = blockIdx.y;
    const int t  = threadIdx.x;
    const int lane = t & 63, wave = t >> 6;

    __shared__ float attn_s[4 * 257];
    __shared__ f32x4 partial[3][64];

#pragma unroll
    for (int q = 0; q < 4; ++q) {
        attn_s[q * 257 + t] = (float)attn[(((long)(b * 12 + cc * 4 + q)) * 256 + i) * 256 + t];
    }
    __syncthreads();

    const int c0 = cc * 256 + lane * 4;
    const float* arow = attn_s + (lane >> 4) * 257;
    const int jb = wave * 64;
    const f32x4* dp = reinterpret_cast<const f32x4*>(d + (long)bi * 196608 + (long)jb * 768 + c0);
    const bf16_t* vp = qkv + (long)b * 589824 + (long)jb * 2304 + 1536 + c0;

    f32x4 acc = {};
#pragma unroll 8
    for (int jj = 0; jj < 64; ++jj) {
        f32x4 dv = __builtin_nontemporal_load(dp + (long)jj * 192);
        bf16x4 vv = *reinterpret_cast<const bf16x4*>(vp + (long)jj * 2304);
        float a = arow[jb + jj];
        acc[0] = fmaf(a, dv[0] + (float)vv[0], acc[0]);
        acc[1] = fmaf(a, dv[1] + (float)vv[1], acc[1]);
        acc[2] = fmaf(a, dv[2] + (float)vv[2], acc[2]);
        acc[3] = fmaf(a, dv[3] + (float)vv[3], acc[3]);
    }

    if (wave) partial[wave - 1][lane] = acc;
    __syncthreads();
    if (wave == 0) {
        acc += partial[0][lane] + partial[1][lane] + partial[2][lane];
        bf16x4 o = { (bf16_t)acc[0], (bf16_t)acc[1], (bf16_t)acc[2], (bf16_t)acc[3] };
        *reinterpret_cast<bf16x4*>(oh + (long)bi * 768 + c0) = o;
    }
}

// ---------------- launch ----------------
extern "C" void kernel_launch(void* const* d_in, const int* in_sizes, int n_in,
                              void* d_out, int out_size, void* d_ws, size_t ws_size,
                              hipStream_t stream) {
    const float* x      = (const float*)d_in[0];   // [2,256,768]
    const float* d      = (const float*)d_in[1];   // [2,256,256,768]
    const float* w_qkv  = (const float*)d_in[2];   // [2304,768]
    const float* w_proj = (const float*)d_in[3];   // [768,768]
    const float* b_proj = (const float*)d_in[4];   // [768]
    float* out = (float*)d_out;                    // [2,256,768]

    char* ws = (char*)d_ws;
    bf16_t* qkvb  = (bf16_t*)(ws);                 //  512x2304 bf16
    bf16_t* probs = (bf16_t*)(ws + 2359296);       //  24x256x256 bf16
    bf16_t* oh    = (bf16_t*)(ws + 5505024);       //  512x768 bf16

    // 1. qkv = x @ w_qkv^T -> bf16 [512,2304]  (288 tiles, XCD-remapped, 2-deep prefetch)
    gemm_bt<float, float, bf16_t, false><<<288, 256, 0, stream>>>(
        x, w_qkv, qkvb, nullptr, 768, 768, 768, 2304);

    // 2. probs = softmax((q/8) k^T) -> bf16 [24,256,256]
    qk_softmax<<<dim3(24, 4), 256, 0, stream>>>(qkvb, probs);

    // 3. oh = attn @ (v + d_pair) -> bf16 [512,768]
    attnd_kernel<<<dim3(512, 3), 256, 0, stream>>>(probs, qkvb, d, oh);

    // 4. out = oh @ w_proj^T + b_proj -> fp32  (96 tiles, XCD-remapped)
    gemm_bt<bf16_t, float, float, true><<<96, 256, 0, stream>>>(
        oh, w_proj, out, b_proj, 768, 768, 768, 768);
}